// Round 16
// baseline (445.338 us; speedup 1.0000x reference)
//
#include <hip/hip_runtime.h>
#include <hip/hip_bf16.h>
#include <cstdint>

#define B_ 4
#define S_ 2048
#define D_ 512
#define H_ 8
#define DH_ 64
#define DFF_ 2048
#define NTOK (B_*S_)
#define EPSF 1e-5f
// sqrt(0.125 * log2(e)) — folded into x so scores come out in exp2 domain
#define XSCALE 0.4246608998f
// 1/XSCALE — undoes the sqrt(c) picked up by V (and the residual path)
#define OSCALE 2.3548200450f

using bf16x8 = __attribute__((ext_vector_type(8))) short;
using bf16x4 = __attribute__((ext_vector_type(4))) short;
using u16x8  = __attribute__((ext_vector_type(8))) unsigned short;
using f32x4  = __attribute__((ext_vector_type(4))) float;
typedef unsigned int uint2v __attribute__((ext_vector_type(2)));

__device__ __forceinline__ ushort f2b(float f) {
  union { __hip_bfloat16 h; ushort u; } cv;
  cv.h = __float2bfloat16(f);
  return cv.u;
}
// round-half-up bf16 truncation (2 VALU ops) — for positive P values only
__device__ __forceinline__ ushort f2bt(float f) {
  return (ushort)((__float_as_uint(f) + 0x8000u) >> 16);
}
__device__ __forceinline__ float b2f(ushort u) {
  union { unsigned int i; float f; } cv;
  cv.i = ((unsigned int)u) << 16;
  return cv.f;
}

// native 2^x (v_exp_f32), no libm edge-case code
__device__ __forceinline__ float fexp2(float x) {
#if __has_builtin(__builtin_amdgcn_exp2f)
  return __builtin_amdgcn_exp2f(x);
#else
  float r;
  asm volatile("v_exp_f32 %0, %1" : "=v"(r) : "v"(x));
  return r;
#endif
}

__device__ __forceinline__ void gload_lds16(const ushort* g, ushort* l) {
  __builtin_amdgcn_global_load_lds(
      (const __attribute__((address_space(1))) void*)g,
      (__attribute__((address_space(3))) void*)l, 16, 0, 0);
}

// K=16 bf16 MFMA (PV step): guarded builtin with fallbacks
__device__ __forceinline__ f32x4 mfma16(bf16x4 a, bf16x4 b, f32x4 c) {
#if __has_builtin(__builtin_amdgcn_mfma_f32_16x16x16_bf16)
  return __builtin_amdgcn_mfma_f32_16x16x16_bf16(a, b, c, 0, 0, 0);
#elif __has_builtin(__builtin_amdgcn_mfma_f32_16x16x16bf16_1k)
  return __builtin_amdgcn_mfma_f32_16x16x16bf16_1k(a, b, c, 0, 0, 0);
#else
  f32x4 d;
  asm volatile("v_mfma_f32_16x16x16_bf16 %0, %1, %2, %3"
               : "=v"(d) : "v"(a), "v"(b), "v"(c));
  return d;
#endif
}

// ---- VALU cross-lane butterflies via permlane*_swap (fallback: shfl) ----
__device__ __forceinline__ float xadd16(float v) {
#if __has_builtin(__builtin_amdgcn_permlane16_swap)
  uint2v r = __builtin_amdgcn_permlane16_swap(__float_as_uint(v), __float_as_uint(v), false, false);
  return __uint_as_float(r.x) + __uint_as_float(r.y);
#else
  return v + __shfl_xor(v, 16);
#endif
}
__device__ __forceinline__ float xadd32(float v) {
#if __has_builtin(__builtin_amdgcn_permlane32_swap)
  uint2v r = __builtin_amdgcn_permlane32_swap(__float_as_uint(v), __float_as_uint(v), false, false);
  return __uint_as_float(r.x) + __uint_as_float(r.y);
#else
  return v + __shfl_xor(v, 32);
#endif
}

// ------- prep: x -> xb/xT (scaled bf16, straight + transposed) -------
__global__ __launch_bounds__(256) void prep_kernel(const float* __restrict__ x,
                                                   ushort* __restrict__ xb,
                                                   ushort* __restrict__ xT) {
  __shared__ ushort T[64 * 72];
  int wg = blockIdx.x;
  int t = threadIdx.x;
  int dt = wg & 7;            // D/64 = 8
  int st = (wg >> 3) & 31;    // S/64 = 32
  int b  = wg >> 8;
  int s0 = st * 64, d0 = dt * 64;
  int r0 = (t >> 4) * 4, cc = (t & 15) * 4;

  ushort4 w[4];
  #pragma unroll
  for (int i = 0; i < 4; ++i) {
    float4 v = *(const float4*)&x[((size_t)b * S_ + s0 + r0 + i) * D_ + d0 + cc];
    w[i] = make_ushort4(f2b(v.x * XSCALE), f2b(v.y * XSCALE),
                        f2b(v.z * XSCALE), f2b(v.w * XSCALE));
    *(ushort4*)&xb[((size_t)b * S_ + s0 + r0 + i) * D_ + d0 + cc] = w[i];
  }
  *(ushort4*)&T[(cc + 0) * 72 + r0] = make_ushort4(w[0].x, w[1].x, w[2].x, w[3].x);
  *(ushort4*)&T[(cc + 1) * 72 + r0] = make_ushort4(w[0].y, w[1].y, w[2].y, w[3].y);
  *(ushort4*)&T[(cc + 2) * 72 + r0] = make_ushort4(w[0].z, w[1].z, w[2].z, w[3].z);
  *(ushort4*)&T[(cc + 3) * 72 + r0] = make_ushort4(w[0].w, w[1].w, w[2].w, w[3].w);
  __syncthreads();
  int dd = t >> 2, sc = (t & 3) * 16;
  ushort* dst = &xT[((size_t)b * D_ + d0 + dd) * S_ + s0 + sc];
  *(u16x8*)dst       = *(const u16x8*)&T[dd * 72 + sc];
  *(u16x8*)(dst + 8) = *(const u16x8*)&T[dd * 72 + sc + 8];
}

// ---------------- flash attention, key-partitioned waves ----------------
// WGs 0..511: QBLK=128, KVBLK=128, 8 waves. Wave w owns keys [16w,16w+16) of
// each tile and computes them against ALL 128 q (Q held in 64 VGPRs).
// P never touches LDS (swapped S^T layout == PV's K=16 B-fragment).
// O is key-partial -> LDS tree-reduction across waves in the epilogue.
// WGs 512..1087: weight fp32->bf16 tail (overlapped, pure VMEM).
__global__ __launch_bounds__(512) void attn_mfma(const ushort* __restrict__ xb,
                                                 const ushort* __restrict__ xT,
                                                 ushort* __restrict__ ctx,
                                                 const float* __restrict__ wa, ushort* __restrict__ da, int na8,
                                                 const float* __restrict__ wb, ushort* __restrict__ db, int nb8,
                                                 const float* __restrict__ wc, ushort* __restrict__ dc, int nc8) {
  __shared__ ushort LDSA[24576];           // 48 KB: KS | KT | QS ; epilogue: f32 red
  ushort* KS = LDSA;                        // [128 keys][64 d]   16 KB
  ushort* KT = LDSA + 8192;                 // [64 d][128 keys]   16 KB (swizzled)
  ushort* QS = LDSA + 16384;                // [128 q][64 d]      16 KB

  int orig = blockIdx.x;
  int t = threadIdx.x;
  if (orig >= 512) {
    int i = (orig - 512) * 512 + t;
    const float* s; ushort* d; int j = i;
    if (j < na8) { s = wa; d = da; }
    else {
      j -= na8;
      if (j < nb8) { s = wb; d = db; }
      else { j -= nb8; if (j >= nc8) return; s = wc; d = dc; }
    }
    const float4* p = (const float4*)(s + (size_t)j * 8);
    float4 v0 = p[0], v1 = p[1];
    *(ushort4*)(d + (size_t)j * 8)     = make_ushort4(f2b(v0.x), f2b(v0.y), f2b(v0.z), f2b(v0.w));
    *(ushort4*)(d + (size_t)j * 8 + 4) = make_ushort4(f2b(v1.x), f2b(v1.y), f2b(v1.z), f2b(v1.w));
    return;
  }

  // XCD-contiguous remap (attn grid slice 512 = 8 * 64)
  int wg = (orig & 7) * 64 + (orig >> 3);
  int qt = wg & 15;
  int hh = (wg >> 4) & 7;
  int b  = wg >> 7;
  int q0 = qt * 128, c0 = hh * DH_;
  int l = t & 63, wv = t >> 6;   // wv 0..7

  const ushort* xbb = xb + (size_t)b * S_ * D_;
  const ushort* xTb = xT + (size_t)b * D_ * S_;

  int rr = l >> 3;            // row within 8-row chunk (64-wide rows)
  int sbk = (l & 7) ^ rr;     // XOR-swizzled source 16B-block (64-wide rows)

  // ---- prologue: stage Q (128x64) into QS; read 16 B-fragments ----
  #pragma unroll
  for (int c = 0; c < 2; ++c) {
    int j = wv * 2 + c;
    gload_lds16(xbb + (size_t)(q0 + j * 8 + rr) * D_ + c0 + sbk * 8, QS + j * 512);
  }
  __syncthreads();
  bf16x8 qf[8][2];
  #pragma unroll
  for (int qb = 0; qb < 8; ++qb) {
    int row = qb * 16 + (l & 15);
    #pragma unroll
    for (int ks = 0; ks < 2; ++ks)
      qf[qb][ks] = *(const bf16x8*)&QS[row * 64 + (((ks * 4 + (l >> 4)) ^ (l & 7)) * 8)];
  }

  // hoisted offsets
  int ksoff[2];     // Ks A-frag (this wave's 16-key slice)
  {
    int row = 16 * wv + (l & 15);
    #pragma unroll
    for (int ks = 0; ks < 2; ++ks)
      ksoff[ks] = row * 64 + (((ks * 4 + (l >> 4)) ^ (row & 7)) * 8);
  }
  int vtoff[4];     // Kt A-frag (V^T): d = m*16+(l&15), keys 16wv + (l>>4)*4..+4
  #pragma unroll
  for (int m = 0; m < 4; ++m) {
    int dd = m * 16 + (l & 15);
    int blk = (2 * wv + ((l >> 4) >> 1)) ^ (dd & 15);
    vtoff[m] = dd * 128 + blk * 8 + ((l >> 4) & 1) * 4;
  }

  f32x4 zero = {0.f, 0.f, 0.f, 0.f};
  f32x4 o[4][8];
  #pragma unroll
  for (int m = 0; m < 4; ++m)
    #pragma unroll
    for (int qb = 0; qb < 8; ++qb) o[m][qb] = zero;
  float l_part[8];
  #pragma unroll
  for (int qb = 0; qb < 8; ++qb) l_part[qb] = 0.f;

  for (int kb = 0; kb < S_ / 128; ++kb) {
    int kr = kb * 128;
    __syncthreads();   // previous tile fully consumed
    // KS: 16 chunks of 8 keys x 64 d; wave stages 2 (its own slice rows)
    #pragma unroll
    for (int c = 0; c < 2; ++c) {
      int j = wv * 2 + c;
      gload_lds16(xbb + (size_t)(kr + j * 8 + rr) * D_ + c0 + sbk * 8, &KS[j * 512]);
    }
    // KT: 16 chunks of 4 d-rows x 128 keys; swizzled 16B-blocks vs (d&15)
    #pragma unroll
    for (int c = 0; c < 2; ++c) {
      int j = wv * 2 + c;
      int dr = j * 4 + (l >> 4);
      int kb16 = (l & 15) ^ (dr & 15);
      gload_lds16(xTb + (size_t)(c0 + dr) * S_ + kr + kb16 * 8, &KT[j * 512]);
    }
    __syncthreads();

    bf16x8 kf0 = *(const bf16x8*)&KS[ksoff[0]];
    bf16x8 kf1 = *(const bf16x8*)&KS[ksoff[1]];
    bf16x4 vt[4];
    #pragma unroll
    for (int m = 0; m < 4; ++m) vt[m] = *(const bf16x4*)&KT[vtoff[m]];

    __builtin_amdgcn_s_setprio(1);
    #pragma unroll
    for (int qb = 0; qb < 8; ++qb) {
      f32x4 st = zero;
      st = __builtin_amdgcn_mfma_f32_16x16x32_bf16(kf0, qf[qb][0], st, 0, 0, 0);
      st = __builtin_amdgcn_mfma_f32_16x16x32_bf16(kf1, qf[qb][1], st, 0, 0, 0);
      float p0 = fexp2(st[0]);
      float p1 = fexp2(st[1]);
      float p2 = fexp2(st[2]);
      float p3 = fexp2(st[3]);
      l_part[qb] += (p0 + p1) + (p2 + p3);
      bf16x4 pb;
      pb[0] = (short)f2bt(p0); pb[1] = (short)f2bt(p1);
      pb[2] = (short)f2bt(p2); pb[3] = (short)f2bt(p3);
      #pragma unroll
      for (int m = 0; m < 4; ++m)
        o[m][qb] = mfma16(vt[m], pb, o[m][qb]);
    }
    __builtin_amdgcn_s_setprio(0);
  }

  // ---- epilogue: cross-wave reduction of O (and l) via LDS, per q-block ----
  // slice layout per wave: 17 rows x 68 f32 (rows 0..15 = q, [64 d + pad];
  // row 16 = per-q l partial). stride 1156 dwords, 8 slices = 37 KB.
  float* red = (float*)LDSA;
  #pragma unroll 1
  for (int qb = 0; qb < 8; ++qb) {
    __syncthreads();   // prior qb reads (or tile loop) done
    #pragma unroll
    for (int m = 0; m < 4; ++m)
      *(f32x4*)&red[wv * 1156 + (l & 15) * 68 + m * 16 + (l >> 4) * 4] = o[m][qb];
    {
      float tl = xadd16(l_part[qb]);
      tl = xadd32(tl);
      if (l < 16) red[wv * 1156 + 16 * 68 + l] = tl;
    }
    __syncthreads();
    // wave wv sums q-rows 2wv, 2wv+1 across all 8 wave-partials
    int qr = 2 * wv + (l >> 5);
    int d2 = (l & 31) * 2;
    float s0 = 0.f, s1 = 0.f, lt = 0.f;
    #pragma unroll
    for (int w2 = 0; w2 < 8; ++w2) {
      float2 v = *(const float2*)&red[w2 * 1156 + qr * 68 + d2];
      s0 += v.x; s1 += v.y;
      lt += red[w2 * 1156 + 16 * 68 + qr];
    }
    float inv = OSCALE / lt;
    size_t qrow = (size_t)b * S_ + q0 + qb * 16 + qr;
    uint pk = ((uint)f2b(s0 * inv)) | (((uint)f2b(s1 * inv)) << 16);
    *(uint*)&ctx[qrow * D_ + c0 + d2] = pk;
  }
}

// ---------------- bf16 MFMA GEMM: C[M,N] = A[M,K] * W[N,K]^T + bias ----------------
// BM=128 fixed; BN (128/64), BK (64/128) templated.
template <int BN, int BK, int RELU, int OUTF32, int OUTB16>
__global__ __launch_bounds__(256) void gemm_bf16(const ushort* __restrict__ A,
                                                 const ushort* __restrict__ Bw,
                                                 const float* __restrict__ bias,
                                                 float* __restrict__ Cf,
                                                 ushort* __restrict__ Cb,
                                                 int M, int N, int K, int ntn) {
  const int NF   = BN / 32;
  const int ACW  = (128 * BK) / 2048;
  const int BCW  = (BN  * BK) / 2048;
  const int RPC  = 512 / BK;
  const int LPR  = BK / 8;
  __shared__ ushort As[128 * BK];
  __shared__ ushort Bs[BN * BK];
  int nwg = gridDim.x;
  int tile = blockIdx.x;
  int cpx = nwg >> 3;
  tile = (tile & 7) * cpx + (tile >> 3);
  int tm = tile / ntn, tn = tile % ntn;
  int m0 = tm * 128, n0 = tn * BN;
  int t = threadIdx.x, l = t & 63, wv = t >> 6;
  int wm = (wv >> 1) * 64, wn = (wv & 1) * (BN / 2);

  f32x4 zero = {0.f, 0.f, 0.f, 0.f};
  f32x4 acc[4][NF];
  #pragma unroll
  for (int m = 0; m < 4; ++m)
    #pragma unroll
    for (int n = 0; n < NF; ++n) acc[m][n] = zero;

  for (int k0 = 0; k0 < K; k0 += BK) {
    __syncthreads();
    #pragma unroll
    for (int c4 = 0; c4 < ACW; ++c4) {
      int jc = wv * ACW + c4;
      int r  = jc * RPC + l / LPR;
      int cs = (l % LPR) ^ (r & 7);
      gload_lds16(A + (size_t)(m0 + r) * K + k0 + cs * 8, &As[jc * 512]);
    }
    #pragma unroll
    for (int c4 = 0; c4 < BCW; ++c4) {
      int jc = wv * BCW + c4;
      int r  = jc * RPC + l / LPR;
      int cs = (l % LPR) ^ (r & 7);
      gload_lds16(Bw + (size_t)(n0 + r) * K + k0 + cs * 8, &Bs[jc * 512]);
    }
    __syncthreads();
    #pragma unroll
    for (int ks = 0; ks < BK / 32; ++ks) {
      bf16x8 af[4], bf[NF];
      #pragma unroll
      for (int m = 0; m < 4; ++m) {
        int r = wm + m * 16 + (l & 15);
        int c = (ks * 4 + (l >> 4)) ^ (r & 7);
        af[m] = *(const bf16x8*)&As[r * BK + c * 8];
      }
      #pragma unroll
      for (int n = 0; n < NF; ++n) {
        int r = wn + n * 16 + (l & 15);
        int c = (ks * 4 + (l >> 4)) ^ (r & 7);
        bf[n] = *(const bf16x8*)&Bs[r * BK + c * 8];
      }
      #pragma unroll
      for (int m = 0; m < 4; ++m)
        #pragma unroll
        for (int n = 0; n < NF; ++n)
          acc[m][n] = __builtin_amdgcn_mfma_f32_16x16x32_bf16(af[m], bf[n], acc[m][n], 0, 0, 0);
    }
  }

  float bv[NF];
  #pragma unroll
  for (int n = 0; n < NF; ++n) bv[n] = bias[n0 + wn + n * 16 + (l & 15)];
  #pragma unroll
  for (int m = 0; m < 4; ++m) {
    int row = m0 + wm + m * 16 + (l >> 4) * 4;
    #pragma unroll
    for (int n = 0; n < NF; ++n) {
      int col = n0 + wn + n * 16 + (l & 15);
      #pragma unroll
      for (int r = 0; r < 4; ++r) {
        float v = acc[m][n][r] + bv[n];
        if (RELU) v = fmaxf(v, 0.f);
        if (OUTF32) Cf[(size_t)(row + r) * N + col] = v;
        if (OUTB16) Cb[(size_t)(row + r) * N + col] = f2b(v);
      }
    }
  }
}

// -------- LayerNorm(bf16 in)*scale+bias + addscale*(bf16 add) -> f32 or bf16 --------
template <int OUTF32>
__global__ __launch_bounds__(256) void ln_b16_kernel(const ushort* __restrict__ in,
                                                     const float* __restrict__ scale,
                                                     const float* __restrict__ bias,
                                                     const ushort* __restrict__ add,
                                                     float addscale,
                                                     float* __restrict__ outf,
                                                     ushort* __restrict__ outb) {
  int row = blockIdx.x * 4 + (threadIdx.x >> 6);
  int lane = threadIdx.x & 63;
  u16x8 iv = *(const u16x8*)&in[(size_t)row * D_ + lane * 8];
  float v[8];
  float sum = 0.f, ss = 0.f;
  #pragma unroll
  for (int i = 0; i < 8; ++i) {
    v[i] = b2f(iv[i]);
    sum += v[i];
    ss += v[i] * v[i];
  }
  #pragma unroll
  for (int off = 1; off < 16; off <<= 1) {
    sum += __shfl_xor(sum, off);
    ss  += __shfl_xor(ss, off);
  }
  sum = xadd16(sum); sum = xadd32(sum);
  ss  = xadd16(ss);  ss  = xadd32(ss);
  float mean = sum * (1.f / D_);
  float var = ss * (1.f / D_) - mean * mean;
  float rstd = rsqrtf(var + EPSF);

  u16x8 av = *(const u16x8*)&add[(size_t)row * D_ + lane * 8];
  float4 s0 = *(const float4*)&scale[lane * 8];
  float4 s1 = *(const float4*)&scale[lane * 8 + 4];
  float4 b0 = *(const float4*)&bias[lane * 8];
  float4 b1 = *(const float4*)&bias[lane * 8 + 4];
  float sc[8] = {s0.x, s0.y, s0.z, s0.w, s1.x, s1.y, s1.z, s1.w};
  float bi[8] = {b0.x, b0.y, b0.z, b0.w, b1.x, b1.y, b1.z, b1.w};
  float o[8];
  #pragma unroll
  for (int i = 0; i < 8; ++i)
    o[i] = (v[i] - mean) * rstd * sc[i] + bi[i] + b2f(av[i]) * addscale;

  if (OUTF32) {
    float* op = outf + (size_t)row * D_ + lane * 8;
    *(float4*)op       = make_float4(o[0], o[1], o[2], o[3]);
    *(float4*)(op + 4) = make_float4(o[4], o[5], o[6], o[7]);
  } else {
    u16x8 ob;
    #pragma unroll
    for (int i = 0; i < 8; ++i) ob[i] = f2b(o[i]);
    *(u16x8*)&outb[(size_t)row * D_ + lane * 8] = ob;
  }
}

extern "C" void kernel_launch(void* const* d_in, const int* in_sizes, int n_in,
                              void* d_out, int out_size, void* d_ws, size_t ws_size,
                              hipStream_t stream) {
  const float* x      = (const float*)d_in[0];
  const float* Wo_w   = (const float*)d_in[3];
  const float* Wo_b   = (const float*)d_in[4];
  const float* ln_a_s = (const float*)d_in[5];
  const float* ln_a_b = (const float*)d_in[6];
  const float* W1_w   = (const float*)d_in[7];
  const float* W1_b   = (const float*)d_in[8];
  const float* W2_w   = (const float*)d_in[9];
  const float* W2_b   = (const float*)d_in[10];
  const float* ln_f_s = (const float*)d_in[11];
  const float* ln_f_b = (const float*)d_in[12];
  float* out = (float*)d_out;

  char* ws = (char*)d_ws;
  const size_t MB = 1024 * 1024;
  ushort* xbb  = (ushort*)(ws);                 // 8 MB   [B,S,D] bf16 (scaled)
  ushort* xTb  = (ushort*)(ws + 8 * MB);        // 8 MB   [B,D,S] bf16 (scaled)
  ushort* wob  = (ushort*)(ws + 16 * MB);       // 0.5 MB
  ushort* w1b  = (ushort*)(ws + 17 * MB);       // 2 MB
  ushort* w2b  = (ushort*)(ws + 19 * MB);       // 2 MB
  ushort* ctxb = (ushort*)(ws + 21 * MB);       // 8 MB
  ushort* x1b  = (ushort*)(ws + 29 * MB);       // 8 MB
  ushort* tmpb = (ushort*)(ws + 37 * MB);       // 8 MB  [NTOK,D] bf16 pre-LN
  ushort* hb   = (ushort*)(ws + 45 * MB);       // 32 MB (ends at 77 MB)

  // x -> bf16 (straight + transposed, pre-scaled)
  prep_kernel<<<B_ * (S_ / 64) * (D_ / 64), 256, 0, stream>>>(x, xbb, xTb);

  // attention (WGs 0..511) + weight cvt tail (WGs 512..1087, overlapped)
  attn_mfma<<<512 + 576, 512, 0, stream>>>(xbb, xTb, ctxb,
                                           Wo_w, wob, (D_ * D_) / 8,
                                           W1_w, w1b, (DFF_ * D_) / 8,
                                           W2_w, w2b, (D_ * DFF_) / 8);

  // attn_out(pre-LN) = ctx @ Wo^T + b -> tmpb (bf16)   [BN=64, BK=128: 512 WGs]
  gemm_bf16<64, 128, 0, 0, 1><<<(NTOK / 128) * (D_ / 64), 256, 0, stream>>>(
      ctxb, wob, Wo_b, nullptr, tmpb, NTOK, D_, D_, D_ / 64);

  // x1 = LN(tmpb) + xbb*OSCALE -> x1b (bf16)
  ln_b16_kernel<0><<<NTOK / 4, 256, 0, stream>>>(tmpb, ln_a_s, ln_a_b, xbb, OSCALE,
                                                 nullptr, x1b);

  // h = relu(x1 @ W1^T + b1) -> hb (bf16)   [BN=128, BK=64: 1024 WGs, 4 WG/CU]
  gemm_bf16<128, 64, 1, 0, 1><<<(NTOK / 128) * (DFF_ / 128), 256, 0, stream>>>(
      x1b, w1b, W1_b, nullptr, hb, NTOK, DFF_, D_, DFF_ / 128);

  // ffn(pre-LN) = h @ W2^T + b2 -> tmpb (bf16)   [BN=64, BK=128: 512 WGs]
  gemm_bf16<64, 128, 0, 0, 1><<<(NTOK / 128) * (D_ / 64), 256, 0, stream>>>(
      hb, w2b, W2_b, nullptr, tmpb, NTOK, D_, DFF_, D_ / 64);

  // out = LN(tmpb) + x1b (f32 final)
  ln_b16_kernel<1><<<NTOK / 4, 256, 0, stream>>>(tmpb, ln_f_s, ln_f_b, x1b, 1.0f,
                                                 out, nullptr);
}

// Round 17
// 151.402 us; speedup vs baseline: 2.9414x; 2.9414x over previous
//
#include <hip/hip_runtime.h>
#include <hip/hip_bf16.h>
#include <cstdint>

#define B_ 4
#define S_ 2048
#define D_ 512
#define H_ 8
#define DH_ 64
#define DFF_ 2048
#define NTOK (B_*S_)
#define EPSF 1e-5f
// sqrt(0.125 * log2(e)) — folded into x so scores come out in exp2 domain
#define XSCALE 0.4246608998f
// 1/XSCALE — undoes the sqrt(c) picked up by V (and the residual path)
#define OSCALE 2.3548200450f

using bf16x8 = __attribute__((ext_vector_type(8))) short;
using bf16x4 = __attribute__((ext_vector_type(4))) short;
using u16x8  = __attribute__((ext_vector_type(8))) unsigned short;
using f32x4  = __attribute__((ext_vector_type(4))) float;
typedef unsigned int uint2v __attribute__((ext_vector_type(2)));

__device__ __forceinline__ ushort f2b(float f) {
  union { __hip_bfloat16 h; ushort u; } cv;
  cv.h = __float2bfloat16(f);
  return cv.u;
}
// round-half-up bf16 truncation (2 VALU ops) — for positive P values only
__device__ __forceinline__ ushort f2bt(float f) {
  return (ushort)((__float_as_uint(f) + 0x8000u) >> 16);
}
__device__ __forceinline__ float b2f(ushort u) {
  union { unsigned int i; float f; } cv;
  cv.i = ((unsigned int)u) << 16;
  return cv.f;
}

// native 2^x (v_exp_f32), no libm edge-case code
__device__ __forceinline__ float fexp2(float x) {
#if __has_builtin(__builtin_amdgcn_exp2f)
  return __builtin_amdgcn_exp2f(x);
#else
  float r;
  asm volatile("v_exp_f32 %0, %1" : "=v"(r) : "v"(x));
  return r;
#endif
}

__device__ __forceinline__ void gload_lds16(const ushort* g, ushort* l) {
  __builtin_amdgcn_global_load_lds(
      (const __attribute__((address_space(1))) void*)g,
      (__attribute__((address_space(3))) void*)l, 16, 0, 0);
}

// K=16 bf16 MFMA (PV step): guarded builtin with fallbacks
__device__ __forceinline__ f32x4 mfma16(bf16x4 a, bf16x4 b, f32x4 c) {
#if __has_builtin(__builtin_amdgcn_mfma_f32_16x16x16_bf16)
  return __builtin_amdgcn_mfma_f32_16x16x16_bf16(a, b, c, 0, 0, 0);
#elif __has_builtin(__builtin_amdgcn_mfma_f32_16x16x16bf16_1k)
  return __builtin_amdgcn_mfma_f32_16x16x16bf16_1k(a, b, c, 0, 0, 0);
#else
  f32x4 d;
  asm volatile("v_mfma_f32_16x16x16_bf16 %0, %1, %2, %3"
               : "=v"(d) : "v"(a), "v"(b), "v"(c));
  return d;
#endif
}

// ---- VALU cross-lane butterflies via permlane*_swap (fallback: shfl) ----
__device__ __forceinline__ float xadd16(float v) {
#if __has_builtin(__builtin_amdgcn_permlane16_swap)
  uint2v r = __builtin_amdgcn_permlane16_swap(__float_as_uint(v), __float_as_uint(v), false, false);
  return __uint_as_float(r.x) + __uint_as_float(r.y);
#else
  return v + __shfl_xor(v, 16);
#endif
}
__device__ __forceinline__ float xadd32(float v) {
#if __has_builtin(__builtin_amdgcn_permlane32_swap)
  uint2v r = __builtin_amdgcn_permlane32_swap(__float_as_uint(v), __float_as_uint(v), false, false);
  return __uint_as_float(r.x) + __uint_as_float(r.y);
#else
  return v + __shfl_xor(v, 32);
#endif
}

// ------- prep: x -> xb/xT (scaled bf16, straight + transposed) -------
__global__ __launch_bounds__(256) void prep_kernel(const float* __restrict__ x,
                                                   ushort* __restrict__ xb,
                                                   ushort* __restrict__ xT) {
  __shared__ ushort T[64 * 72];
  int wg = blockIdx.x;
  int t = threadIdx.x;
  int dt = wg & 7;            // D/64 = 8
  int st = (wg >> 3) & 31;    // S/64 = 32
  int b  = wg >> 8;
  int s0 = st * 64, d0 = dt * 64;
  int r0 = (t >> 4) * 4, cc = (t & 15) * 4;

  ushort4 w[4];
  #pragma unroll
  for (int i = 0; i < 4; ++i) {
    float4 v = *(const float4*)&x[((size_t)b * S_ + s0 + r0 + i) * D_ + d0 + cc];
    w[i] = make_ushort4(f2b(v.x * XSCALE), f2b(v.y * XSCALE),
                        f2b(v.z * XSCALE), f2b(v.w * XSCALE));
    *(ushort4*)&xb[((size_t)b * S_ + s0 + r0 + i) * D_ + d0 + cc] = w[i];
  }
  *(ushort4*)&T[(cc + 0) * 72 + r0] = make_ushort4(w[0].x, w[1].x, w[2].x, w[3].x);
  *(ushort4*)&T[(cc + 1) * 72 + r0] = make_ushort4(w[0].y, w[1].y, w[2].y, w[3].y);
  *(ushort4*)&T[(cc + 2) * 72 + r0] = make_ushort4(w[0].z, w[1].z, w[2].z, w[3].z);
  *(ushort4*)&T[(cc + 3) * 72 + r0] = make_ushort4(w[0].w, w[1].w, w[2].w, w[3].w);
  __syncthreads();
  int dd = t >> 2, sc = (t & 3) * 16;
  ushort* dst = &xT[((size_t)b * D_ + d0 + dd) * S_ + s0 + sc];
  *(u16x8*)dst       = *(const u16x8*)&T[dd * 72 + sc];
  *(u16x8*)(dst + 8) = *(const u16x8*)&T[dd * 72 + sc + 8];
}

// ---------------- flash attention, key-partitioned waves ----------------
// WGs 0..511: QBLK=128, KVBLK=128, 8 waves. Wave w owns keys [16w,16w+16) of
// each tile and computes them against ALL 128 q (Q held in 64 VGPRs).
// P never touches LDS (swapped S^T layout == PV's K=16 B-fragment).
// O is key-partial -> LDS tree-reduction across waves in the epilogue
// (FULLY UNROLLED: all o/l indices compile-time — rule #20, no scratch demotion).
// WGs 512..1087: weight fp32->bf16 tail (overlapped, pure VMEM).
__global__ __launch_bounds__(512) void attn_mfma(const ushort* __restrict__ xb,
                                                 const ushort* __restrict__ xT,
                                                 ushort* __restrict__ ctx,
                                                 const float* __restrict__ wa, ushort* __restrict__ da, int na8,
                                                 const float* __restrict__ wb, ushort* __restrict__ db, int nb8,
                                                 const float* __restrict__ wc, ushort* __restrict__ dc, int nc8) {
  __shared__ ushort LDSA[24576];           // 48 KB: KS | KT | QS ; epilogue: f32 red
  ushort* KS = LDSA;                        // [128 keys][64 d]   16 KB
  ushort* KT = LDSA + 8192;                 // [64 d][128 keys]   16 KB (swizzled)
  ushort* QS = LDSA + 16384;                // [128 q][64 d]      16 KB

  int orig = blockIdx.x;
  int t = threadIdx.x;
  if (orig >= 512) {
    int i = (orig - 512) * 512 + t;
    const float* s; ushort* d; int j = i;
    if (j < na8) { s = wa; d = da; }
    else {
      j -= na8;
      if (j < nb8) { s = wb; d = db; }
      else { j -= nb8; if (j >= nc8) return; s = wc; d = dc; }
    }
    const float4* p = (const float4*)(s + (size_t)j * 8);
    float4 v0 = p[0], v1 = p[1];
    *(ushort4*)(d + (size_t)j * 8)     = make_ushort4(f2b(v0.x), f2b(v0.y), f2b(v0.z), f2b(v0.w));
    *(ushort4*)(d + (size_t)j * 8 + 4) = make_ushort4(f2b(v1.x), f2b(v1.y), f2b(v1.z), f2b(v1.w));
    return;
  }

  // XCD-contiguous remap (attn grid slice 512 = 8 * 64)
  int wg = (orig & 7) * 64 + (orig >> 3);
  int qt = wg & 15;
  int hh = (wg >> 4) & 7;
  int b  = wg >> 7;
  int q0 = qt * 128, c0 = hh * DH_;
  int l = t & 63, wv = t >> 6;   // wv 0..7

  const ushort* xbb = xb + (size_t)b * S_ * D_;
  const ushort* xTb = xT + (size_t)b * D_ * S_;

  int rr = l >> 3;            // row within 8-row chunk (64-wide rows)
  int sbk = (l & 7) ^ rr;     // XOR-swizzled source 16B-block (64-wide rows)

  // ---- prologue: stage Q (128x64) into QS; read 16 B-fragments ----
  #pragma unroll
  for (int c = 0; c < 2; ++c) {
    int j = wv * 2 + c;
    gload_lds16(xbb + (size_t)(q0 + j * 8 + rr) * D_ + c0 + sbk * 8, QS + j * 512);
  }
  __syncthreads();
  bf16x8 qf[8][2];
  #pragma unroll
  for (int qb = 0; qb < 8; ++qb) {
    int row = qb * 16 + (l & 15);
    #pragma unroll
    for (int ks = 0; ks < 2; ++ks)
      qf[qb][ks] = *(const bf16x8*)&QS[row * 64 + (((ks * 4 + (l >> 4)) ^ (l & 7)) * 8)];
  }

  // hoisted offsets
  int ksoff[2];     // Ks A-frag (this wave's 16-key slice)
  {
    int row = 16 * wv + (l & 15);
    #pragma unroll
    for (int ks = 0; ks < 2; ++ks)
      ksoff[ks] = row * 64 + (((ks * 4 + (l >> 4)) ^ (row & 7)) * 8);
  }
  int vtoff[4];     // Kt A-frag (V^T): d = m*16+(l&15), keys 16wv + (l>>4)*4..+4
  #pragma unroll
  for (int m = 0; m < 4; ++m) {
    int dd = m * 16 + (l & 15);
    int blk = (2 * wv + ((l >> 4) >> 1)) ^ (dd & 15);
    vtoff[m] = dd * 128 + blk * 8 + ((l >> 4) & 1) * 4;
  }

  f32x4 zero = {0.f, 0.f, 0.f, 0.f};
  f32x4 o[4][8];
  #pragma unroll
  for (int m = 0; m < 4; ++m)
    #pragma unroll
    for (int qb = 0; qb < 8; ++qb) o[m][qb] = zero;
  float l_part[8];
  #pragma unroll
  for (int qb = 0; qb < 8; ++qb) l_part[qb] = 0.f;

  for (int kb = 0; kb < S_ / 128; ++kb) {
    int kr = kb * 128;
    __syncthreads();   // previous tile fully consumed
    // KS: 16 chunks of 8 keys x 64 d; wave stages 2 (its own slice rows)
    #pragma unroll
    for (int c = 0; c < 2; ++c) {
      int j = wv * 2 + c;
      gload_lds16(xbb + (size_t)(kr + j * 8 + rr) * D_ + c0 + sbk * 8, &KS[j * 512]);
    }
    // KT: 16 chunks of 4 d-rows x 128 keys; swizzled 16B-blocks vs (d&15)
    #pragma unroll
    for (int c = 0; c < 2; ++c) {
      int j = wv * 2 + c;
      int dr = j * 4 + (l >> 4);
      int kb16 = (l & 15) ^ (dr & 15);
      gload_lds16(xTb + (size_t)(c0 + dr) * S_ + kr + kb16 * 8, &KT[j * 512]);
    }
    __syncthreads();

    bf16x8 kf0 = *(const bf16x8*)&KS[ksoff[0]];
    bf16x8 kf1 = *(const bf16x8*)&KS[ksoff[1]];
    bf16x4 vt[4];
    #pragma unroll
    for (int m = 0; m < 4; ++m) vt[m] = *(const bf16x4*)&KT[vtoff[m]];

    __builtin_amdgcn_s_setprio(1);
    #pragma unroll
    for (int qb = 0; qb < 8; ++qb) {
      f32x4 st = zero;
      st = __builtin_amdgcn_mfma_f32_16x16x32_bf16(kf0, qf[qb][0], st, 0, 0, 0);
      st = __builtin_amdgcn_mfma_f32_16x16x32_bf16(kf1, qf[qb][1], st, 0, 0, 0);
      float p0 = fexp2(st[0]);
      float p1 = fexp2(st[1]);
      float p2 = fexp2(st[2]);
      float p3 = fexp2(st[3]);
      l_part[qb] += (p0 + p1) + (p2 + p3);
      bf16x4 pb;
      pb[0] = (short)f2bt(p0); pb[1] = (short)f2bt(p1);
      pb[2] = (short)f2bt(p2); pb[3] = (short)f2bt(p3);
      #pragma unroll
      for (int m = 0; m < 4; ++m)
        o[m][qb] = mfma16(vt[m], pb, o[m][qb]);
    }
    __builtin_amdgcn_s_setprio(0);
  }

  // ---- epilogue: cross-wave reduction of O (and l) via LDS, per q-block ----
  // FULLY UNROLLED so every o[m][qb] / l_part[qb] index is compile-time.
  float* red = (float*)LDSA;
  #pragma unroll
  for (int qb = 0; qb < 8; ++qb) {
    __syncthreads();   // prior qb reads (or tile loop) done
    #pragma unroll
    for (int m = 0; m < 4; ++m)
      *(f32x4*)&red[wv * 1156 + (l & 15) * 68 + m * 16 + (l >> 4) * 4] = o[m][qb];
    {
      float tl = xadd16(l_part[qb]);
      tl = xadd32(tl);
      if (l < 16) red[wv * 1156 + 16 * 68 + l] = tl;
    }
    __syncthreads();
    // wave wv sums q-rows 2wv, 2wv+1 across all 8 wave-partials
    int qr = 2 * wv + (l >> 5);
    int d2 = (l & 31) * 2;
    float s0 = 0.f, s1 = 0.f, lt = 0.f;
    #pragma unroll
    for (int w2 = 0; w2 < 8; ++w2) {
      float2 v = *(const float2*)&red[w2 * 1156 + qr * 68 + d2];
      s0 += v.x; s1 += v.y;
      lt += red[w2 * 1156 + 16 * 68 + qr];
    }
    float inv = OSCALE / lt;
    size_t qrow = (size_t)b * S_ + q0 + qb * 16 + qr;
    uint pk = ((uint)f2b(s0 * inv)) | (((uint)f2b(s1 * inv)) << 16);
    *(uint*)&ctx[qrow * D_ + c0 + d2] = pk;
  }
}

// ---------------- bf16 MFMA GEMM: C[M,N] = A[M,K] * W[N,K]^T + bias ----------------
// BM=128 fixed; BN (128/64), BK (64/128) templated.
template <int BN, int BK, int RELU, int OUTF32, int OUTB16>
__global__ __launch_bounds__(256) void gemm_bf16(const ushort* __restrict__ A,
                                                 const ushort* __restrict__ Bw,
                                                 const float* __restrict__ bias,
                                                 float* __restrict__ Cf,
                                                 ushort* __restrict__ Cb,
                                                 int M, int N, int K, int ntn) {
  const int NF   = BN / 32;
  const int ACW  = (128 * BK) / 2048;
  const int BCW  = (BN  * BK) / 2048;
  const int RPC  = 512 / BK;
  const int LPR  = BK / 8;
  __shared__ ushort As[128 * BK];
  __shared__ ushort Bs[BN * BK];
  int nwg = gridDim.x;
  int tile = blockIdx.x;
  int cpx = nwg >> 3;
  tile = (tile & 7) * cpx + (tile >> 3);
  int tm = tile / ntn, tn = tile % ntn;
  int m0 = tm * 128, n0 = tn * BN;
  int t = threadIdx.x, l = t & 63, wv = t >> 6;
  int wm = (wv >> 1) * 64, wn = (wv & 1) * (BN / 2);

  f32x4 zero = {0.f, 0.f, 0.f, 0.f};
  f32x4 acc[4][NF];
  #pragma unroll
  for (int m = 0; m < 4; ++m)
    #pragma unroll
    for (int n = 0; n < NF; ++n) acc[m][n] = zero;

  for (int k0 = 0; k0 < K; k0 += BK) {
    __syncthreads();
    #pragma unroll
    for (int c4 = 0; c4 < ACW; ++c4) {
      int jc = wv * ACW + c4;
      int r  = jc * RPC + l / LPR;
      int cs = (l % LPR) ^ (r & 7);
      gload_lds16(A + (size_t)(m0 + r) * K + k0 + cs * 8, &As[jc * 512]);
    }
    #pragma unroll
    for (int c4 = 0; c4 < BCW; ++c4) {
      int jc = wv * BCW + c4;
      int r  = jc * RPC + l / LPR;
      int cs = (l % LPR) ^ (r & 7);
      gload_lds16(Bw + (size_t)(n0 + r) * K + k0 + cs * 8, &Bs[jc * 512]);
    }
    __syncthreads();
    #pragma unroll
    for (int ks = 0; ks < BK / 32; ++ks) {
      bf16x8 af[4], bf[NF];
      #pragma unroll
      for (int m = 0; m < 4; ++m) {
        int r = wm + m * 16 + (l & 15);
        int c = (ks * 4 + (l >> 4)) ^ (r & 7);
        af[m] = *(const bf16x8*)&As[r * BK + c * 8];
      }
      #pragma unroll
      for (int n = 0; n < NF; ++n) {
        int r = wn + n * 16 + (l & 15);
        int c = (ks * 4 + (l >> 4)) ^ (r & 7);
        bf[n] = *(const bf16x8*)&Bs[r * BK + c * 8];
      }
      #pragma unroll
      for (int m = 0; m < 4; ++m)
        #pragma unroll
        for (int n = 0; n < NF; ++n)
          acc[m][n] = __builtin_amdgcn_mfma_f32_16x16x32_bf16(af[m], bf[n], acc[m][n], 0, 0, 0);
    }
  }

  float bv[NF];
  #pragma unroll
  for (int n = 0; n < NF; ++n) bv[n] = bias[n0 + wn + n * 16 + (l & 15)];
  #pragma unroll
  for (int m = 0; m < 4; ++m) {
    int row = m0 + wm + m * 16 + (l >> 4) * 4;
    #pragma unroll
    for (int n = 0; n < NF; ++n) {
      int col = n0 + wn + n * 16 + (l & 15);
      #pragma unroll
      for (int r = 0; r < 4; ++r) {
        float v = acc[m][n][r] + bv[n];
        if (RELU) v = fmaxf(v, 0.f);
        if (OUTF32) Cf[(size_t)(row + r) * N + col] = v;
        if (OUTB16) Cb[(size_t)(row + r) * N + col] = f2b(v);
      }
    }
  }
}

// -------- LayerNorm(bf16 in)*scale+bias + addscale*(bf16 add) -> f32 or bf16 --------
template <int OUTF32>
__global__ __launch_bounds__(256) void ln_b16_kernel(const ushort* __restrict__ in,
                                                     const float* __restrict__ scale,
                                                     const float* __restrict__ bias,
                                                     const ushort* __restrict__ add,
                                                     float addscale,
                                                     float* __restrict__ outf,
                                                     ushort* __restrict__ outb) {
  int row = blockIdx.x * 4 + (threadIdx.x >> 6);
  int lane = threadIdx.x & 63;
  u16x8 iv = *(const u16x8*)&in[(size_t)row * D_ + lane * 8];
  float v[8];
  float sum = 0.f, ss = 0.f;
  #pragma unroll
  for (int i = 0; i < 8; ++i) {
    v[i] = b2f(iv[i]);
    sum += v[i];
    ss += v[i] * v[i];
  }
  #pragma unroll
  for (int off = 1; off < 16; off <<= 1) {
    sum += __shfl_xor(sum, off);
    ss  += __shfl_xor(ss, off);
  }
  sum = xadd16(sum); sum = xadd32(sum);
  ss  = xadd16(ss);  ss  = xadd32(ss);
  float mean = sum * (1.f / D_);
  float var = ss * (1.f / D_) - mean * mean;
  float rstd = rsqrtf(var + EPSF);

  u16x8 av = *(const u16x8*)&add[(size_t)row * D_ + lane * 8];
  float4 s0 = *(const float4*)&scale[lane * 8];
  float4 s1 = *(const float4*)&scale[lane * 8 + 4];
  float4 b0 = *(const float4*)&bias[lane * 8];
  float4 b1 = *(const float4*)&bias[lane * 8 + 4];
  float sc[8] = {s0.x, s0.y, s0.z, s0.w, s1.x, s1.y, s1.z, s1.w};
  float bi[8] = {b0.x, b0.y, b0.z, b0.w, b1.x, b1.y, b1.z, b1.w};
  float o[8];
  #pragma unroll
  for (int i = 0; i < 8; ++i)
    o[i] = (v[i] - mean) * rstd * sc[i] + bi[i] + b2f(av[i]) * addscale;

  if (OUTF32) {
    float* op = outf + (size_t)row * D_ + lane * 8;
    *(float4*)op       = make_float4(o[0], o[1], o[2], o[3]);
    *(float4*)(op + 4) = make_float4(o[4], o[5], o[6], o[7]);
  } else {
    u16x8 ob;
    #pragma unroll
    for (int i = 0; i < 8; ++i) ob[i] = f2b(o[i]);
    *(u16x8*)&outb[(size_t)row * D_ + lane * 8] = ob;
  }
}

extern "C" void kernel_launch(void* const* d_in, const int* in_sizes, int n_in,
                              void* d_out, int out_size, void* d_ws, size_t ws_size,
                              hipStream_t stream) {
  const float* x      = (const float*)d_in[0];
  const float* Wo_w   = (const float*)d_in[3];
  const float* Wo_b   = (const float*)d_in[4];
  const float* ln_a_s = (const float*)d_in[5];
  const float* ln_a_b = (const float*)d_in[6];
  const float* W1_w   = (const float*)d_in[7];
  const float* W1_b   = (const float*)d_in[8];
  const float* W2_w   = (const float*)d_in[9];
  const float* W2_b   = (const float*)d_in[10];
  const float* ln_f_s = (const float*)d_in[11];
  const float* ln_f_b = (const float*)d_in[12];
  float* out = (float*)d_out;

  char* ws = (char*)d_ws;
  const size_t MB = 1024 * 1024;
  ushort* xbb  = (ushort*)(ws);                 // 8 MB   [B,S,D] bf16 (scaled)
  ushort* xTb  = (ushort*)(ws + 8 * MB);        // 8 MB   [B,D,S] bf16 (scaled)
  ushort* wob  = (ushort*)(ws + 16 * MB);       // 0.5 MB
  ushort* w1b  = (ushort*)(ws + 17 * MB);       // 2 MB
  ushort* w2b  = (ushort*)(ws + 19 * MB);       // 2 MB
  ushort* ctxb = (ushort*)(ws + 21 * MB);       // 8 MB
  ushort* x1b  = (ushort*)(ws + 29 * MB);       // 8 MB
  ushort* tmpb = (ushort*)(ws + 37 * MB);       // 8 MB  [NTOK,D] bf16 pre-LN
  ushort* hb   = (ushort*)(ws + 45 * MB);       // 32 MB (ends at 77 MB)

  // x -> bf16 (straight + transposed, pre-scaled)
  prep_kernel<<<B_ * (S_ / 64) * (D_ / 64), 256, 0, stream>>>(x, xbb, xTb);

  // attention (WGs 0..511) + weight cvt tail (WGs 512..1087, overlapped)
  attn_mfma<<<512 + 576, 512, 0, stream>>>(xbb, xTb, ctxb,
                                           Wo_w, wob, (D_ * D_) / 8,
                                           W1_w, w1b, (DFF_ * D_) / 8,
                                           W2_w, w2b, (D_ * DFF_) / 8);

  // attn_out(pre-LN) = ctx @ Wo^T + b -> tmpb (bf16)   [BN=64, BK=128: 512 WGs]
  gemm_bf16<64, 128, 0, 0, 1><<<(NTOK / 128) * (D_ / 64), 256, 0, stream>>>(
      ctxb, wob, Wo_b, nullptr, tmpb, NTOK, D_, D_, D_ / 64);

  // x1 = LN(tmpb) + xbb*OSCALE -> x1b (bf16)
  ln_b16_kernel<0><<<NTOK / 4, 256, 0, stream>>>(tmpb, ln_a_s, ln_a_b, xbb, OSCALE,
                                                 nullptr, x1b);

  // h = relu(x1 @ W1^T + b1) -> hb (bf16)   [BN=128, BK=64: 1024 WGs, 4 WG/CU]
  gemm_bf16<128, 64, 1, 0, 1><<<(NTOK / 128) * (DFF_ / 128), 256, 0, stream>>>(
      x1b, w1b, W1_b, nullptr, hb, NTOK, DFF_, D_, DFF_ / 128);

  // ffn(pre-LN) = h @ W2^T + b2 -> tmpb (bf16)   [BN=64, BK=128: 512 WGs]
  gemm_bf16<64, 128, 0, 0, 1><<<(NTOK / 128) * (D_ / 64), 256, 0, stream>>>(
      hb, w2b, W2_b, nullptr, tmpb, NTOK, D_, DFF_, D_ / 64);

  // out = LN(tmpb) + x1b (f32 final)
  ln_b16_kernel<1><<<NTOK / 4, 256, 0, stream>>>(tmpb, ln_f_s, ln_f_b, x1b, 1.0f,
                                                 out, nullptr);
}

// Round 18
// 130.588 us; speedup vs baseline: 3.4102x; 1.1594x over previous
//
#include <hip/hip_runtime.h>
#include <hip/hip_bf16.h>
#include <cstdint>

#define B_ 4
#define S_ 2048
#define D_ 512
#define H_ 8
#define DH_ 64
#define DFF_ 2048
#define NTOK (B_*S_)
#define EPSF 1e-5f
// sqrt(0.125 * log2(e)) — folded into x so scores come out in exp2 domain
#define XSCALE 0.4246608998f
// 1/XSCALE — undoes the sqrt(c) picked up by V (and the residual path)
#define OSCALE 2.3548200450f

using bf16x8 = __attribute__((ext_vector_type(8))) short;
using u16x8  = __attribute__((ext_vector_type(8))) unsigned short;
using f32x4  = __attribute__((ext_vector_type(4))) float;
typedef unsigned int uint2v __attribute__((ext_vector_type(2)));

__device__ __forceinline__ ushort f2b(float f) {
  union { __hip_bfloat16 h; ushort u; } cv;
  cv.h = __float2bfloat16(f);
  return cv.u;
}
// round-half-up bf16 truncation (2 VALU ops) — for positive P values only
__device__ __forceinline__ ushort f2bt(float f) {
  return (ushort)((__float_as_uint(f) + 0x8000u) >> 16);
}
__device__ __forceinline__ float b2f(ushort u) {
  union { unsigned int i; float f; } cv;
  cv.i = ((unsigned int)u) << 16;
  return cv.f;
}

// native 2^x (v_exp_f32), no libm edge-case code
__device__ __forceinline__ float fexp2(float x) {
#if __has_builtin(__builtin_amdgcn_exp2f)
  return __builtin_amdgcn_exp2f(x);
#else
  float r;
  asm volatile("v_exp_f32 %0, %1" : "=v"(r) : "v"(x));
  return r;
#endif
}

__device__ __forceinline__ void gload_lds16(const ushort* g, ushort* l) {
  __builtin_amdgcn_global_load_lds(
      (const __attribute__((address_space(1))) void*)g,
      (__attribute__((address_space(3))) void*)l, 16, 0, 0);
}

// ---- VALU cross-lane butterflies via permlane*_swap (fallback: shfl) ----
__device__ __forceinline__ float xadd16(float v) {
#if __has_builtin(__builtin_amdgcn_permlane16_swap)
  uint2v r = __builtin_amdgcn_permlane16_swap(__float_as_uint(v), __float_as_uint(v), false, false);
  return __uint_as_float(r.x) + __uint_as_float(r.y);
#else
  return v + __shfl_xor(v, 16);
#endif
}
__device__ __forceinline__ float xadd32(float v) {
#if __has_builtin(__builtin_amdgcn_permlane32_swap)
  uint2v r = __builtin_amdgcn_permlane32_swap(__float_as_uint(v), __float_as_uint(v), false, false);
  return __uint_as_float(r.x) + __uint_as_float(r.y);
#else
  return v + __shfl_xor(v, 32);
#endif
}

// ------- prep: x -> xb/xT (scaled bf16, straight + transposed) -------
__global__ __launch_bounds__(256) void prep_kernel(const float* __restrict__ x,
                                                   ushort* __restrict__ xb,
                                                   ushort* __restrict__ xT) {
  __shared__ ushort T[64 * 72];
  int wg = blockIdx.x;
  int t = threadIdx.x;
  int dt = wg & 7;            // D/64 = 8
  int st = (wg >> 3) & 31;    // S/64 = 32
  int b  = wg >> 8;
  int s0 = st * 64, d0 = dt * 64;
  int r0 = (t >> 4) * 4, cc = (t & 15) * 4;

  ushort4 w[4];
  #pragma unroll
  for (int i = 0; i < 4; ++i) {
    float4 v = *(const float4*)&x[((size_t)b * S_ + s0 + r0 + i) * D_ + d0 + cc];
    w[i] = make_ushort4(f2b(v.x * XSCALE), f2b(v.y * XSCALE),
                        f2b(v.z * XSCALE), f2b(v.w * XSCALE));
    *(ushort4*)&xb[((size_t)b * S_ + s0 + r0 + i) * D_ + d0 + cc] = w[i];
  }
  *(ushort4*)&T[(cc + 0) * 72 + r0] = make_ushort4(w[0].x, w[1].x, w[2].x, w[3].x);
  *(ushort4*)&T[(cc + 1) * 72 + r0] = make_ushort4(w[0].y, w[1].y, w[2].y, w[3].y);
  *(ushort4*)&T[(cc + 2) * 72 + r0] = make_ushort4(w[0].z, w[1].z, w[2].z, w[3].z);
  *(ushort4*)&T[(cc + 3) * 72 + r0] = make_ushort4(w[0].w, w[1].w, w[2].w, w[3].w);
  __syncthreads();
  int dd = t >> 2, sc = (t & 3) * 16;
  ushort* dst = &xT[((size_t)b * D_ + d0 + dd) * S_ + s0 + sc];
  *(u16x8*)dst       = *(const u16x8*)&T[dd * 72 + sc];
  *(u16x8*)(dst + 8) = *(const u16x8*)&T[dd * 72 + sc + 8];
}

// ---------------- flash attention (WGs 0..511) + weight cvt (WGs 512..1087) ----------------
// Attn: QBLK=128, dbuf + counted vmcnt, 8 waves; softmax/PV split into two
// 32-key halves (wave-local reorder — exp of half 1 overlaps PV of half 0).
__global__ __launch_bounds__(512) void attn_mfma(const ushort* __restrict__ xb,
                                                 const ushort* __restrict__ xT,
                                                 ushort* __restrict__ ctx,
                                                 const float* __restrict__ wa, ushort* __restrict__ da, int na8,
                                                 const float* __restrict__ wb, ushort* __restrict__ db, int nb8,
                                                 const float* __restrict__ wc, ushort* __restrict__ dc, int nc8) {
  __shared__ ushort Ks[2][64 * 64];   // 16 KB
  __shared__ ushort Kt[2][64 * 64];   // 16 KB
  __shared__ ushort Ps[8][16 * 72];   // 18 KB; first 16 KB reused as Q staging

  int orig = blockIdx.x;
  int t = threadIdx.x;
  if (orig >= 512) {
    // ---- weight fp32 -> bf16 tail (overlaps attn WGs) ----
    int i = (orig - 512) * 512 + t;
    const float* s; ushort* d; int j = i;
    if (j < na8) { s = wa; d = da; }
    else {
      j -= na8;
      if (j < nb8) { s = wb; d = db; }
      else { j -= nb8; if (j >= nc8) return; s = wc; d = dc; }
    }
    const float4* p = (const float4*)(s + (size_t)j * 8);
    float4 v0 = p[0], v1 = p[1];
    *(ushort4*)(d + (size_t)j * 8)     = make_ushort4(f2b(v0.x), f2b(v0.y), f2b(v0.z), f2b(v0.w));
    *(ushort4*)(d + (size_t)j * 8 + 4) = make_ushort4(f2b(v1.x), f2b(v1.y), f2b(v1.z), f2b(v1.w));
    return;
  }

  // XCD-contiguous remap (attn grid slice 512 = 8 * 64)
  int wg = (orig & 7) * 64 + (orig >> 3);
  int qt = wg & 15;
  int hh = (wg >> 4) & 7;
  int b  = wg >> 7;
  int q0 = qt * 128, c0 = hh * DH_;
  int l = t & 63, wv = t >> 6;   // wv 0..7

  const ushort* xbb = xb + (size_t)b * S_ * D_;
  const ushort* xTb = xT + (size_t)b * D_ * S_;

  int rr = l >> 3;            // row within 8-row chunk
  int sbk = (l & 7) ^ rr;     // XOR-swizzled source 16B-block

  auto issueKT = [&](int kr, int bf) {
    gload_lds16(xbb + (size_t)(kr + wv * 8 + rr) * D_ + c0 + sbk * 8, &Ks[bf][wv * 512]);
    gload_lds16(xTb + (size_t)(c0 + wv * 8 + rr) * S_ + kr + sbk * 8, &Kt[bf][wv * 512]);
  };

  // ---- prologue: stage Q (128x64) + tile 0 ----
  ushort* Qlds = (ushort*)Ps;
  #pragma unroll
  for (int c = 0; c < 2; ++c) {
    int j = wv * 2 + c;
    gload_lds16(xbb + (size_t)(q0 + j * 8 + rr) * D_ + c0 + sbk * 8, Qlds + j * 512);
  }
  issueKT(0, 0);
  asm volatile("s_waitcnt vmcnt(0)" ::: "memory");
  __builtin_amdgcn_s_barrier();
  asm volatile("" ::: "memory");

  bf16x8 qf[2];
  {
    int row = wv * 16 + (l & 15);
    #pragma unroll
    for (int ks = 0; ks < 2; ++ks)
      qf[ks] = *(const bf16x8*)&Qlds[row * 64 + (((ks * 4 + (l >> 4)) ^ (row & 7)) * 8)];
  }

  // hoisted, loop-invariant swizzled LDS element-offsets
  int koff[2][4], poff[2];
  #pragma unroll
  for (int ks = 0; ks < 2; ++ks) {
    #pragma unroll
    for (int m = 0; m < 4; ++m) {
      int row = m * 16 + (l & 15);
      koff[ks][m] = row * 64 + (((ks * 4 + (l >> 4)) ^ (row & 7)) * 8);
    }
    poff[ks] = (l & 15) * 72 + ks * 32 + (l >> 4) * 8;
  }

  float l_i = 0.f;
  f32x4 zero = {0.f, 0.f, 0.f, 0.f};
  f32x4 ot[4];
  #pragma unroll
  for (int m = 0; m < 4; ++m) ot[m] = zero;

  auto compute = [&](int bf) {
    // ---- S^T = K * Q^T ----
    f32x4 st[4];
    #pragma unroll
    for (int m = 0; m < 4; ++m) st[m] = zero;
    __builtin_amdgcn_s_setprio(1);
    #pragma unroll
    for (int ks = 0; ks < 2; ++ks) {
      #pragma unroll
      for (int m = 0; m < 4; ++m) {
        bf16x8 kf = *(const bf16x8*)&Ks[bf][koff[ks][m]];
        st[m] = __builtin_amdgcn_mfma_f32_16x16x32_bf16(kf, qf[ks], st[m], 0, 0, 0);
      }
    }
    __builtin_amdgcn_s_setprio(0);

    // ---- softmax + PV in two 32-key halves (wave-local; half h's P writes
    //      for m = 2h, 2h+1 exactly cover the ks=h read range) ----
    float rs = 0.f;
    #pragma unroll
    for (int h = 0; h < 2; ++h) {
      ushort4 pw[2];
      #pragma unroll
      for (int mm = 0; mm < 2; ++mm) {
        int m = h * 2 + mm;
        float p0 = fexp2(st[m][0]);
        float p1 = fexp2(st[m][1]);
        float p2 = fexp2(st[m][2]);
        float p3 = fexp2(st[m][3]);
        rs += (p0 + p1) + (p2 + p3);
        pw[mm] = make_ushort4(f2bt(p0), f2bt(p1), f2bt(p2), f2bt(p3));
      }
      #pragma unroll
      for (int mm = 0; mm < 2; ++mm) {
        int m = h * 2 + mm;
        *(ushort4*)&Ps[wv][(l & 15) * 72 + m * 16 + (l >> 4) * 4] = pw[mm];
      }
      bf16x8 pf = *(const bf16x8*)&Ps[wv][poff[h]];
      __builtin_amdgcn_s_setprio(1);
      #pragma unroll
      for (int m = 0; m < 4; ++m) {
        bf16x8 vf = *(const bf16x8*)&Kt[bf][koff[h][m]];
        ot[m] = __builtin_amdgcn_mfma_f32_16x16x32_bf16(vf, pf, ot[m], 0, 0, 0);
      }
      __builtin_amdgcn_s_setprio(0);
    }
    l_i += rs;
  };

  // ---- main loop: prefetch t+1, counted vmcnt(2) (t+1's loads stay in flight) ----
  for (int kb = 0; kb < 31; ++kb) {
    issueKT((kb + 1) * 64, (kb + 1) & 1);
    asm volatile("s_waitcnt vmcnt(2)" ::: "memory");
    __builtin_amdgcn_s_barrier();
    asm volatile("" ::: "memory");
    compute(kb & 1);
    asm volatile("" ::: "memory");
    __builtin_amdgcn_s_barrier();
  }
  asm volatile("s_waitcnt vmcnt(0)" ::: "memory");
  __builtin_amdgcn_s_barrier();
  asm volatile("" ::: "memory");
  compute(1);

  // ---- final l reduction (lanes q, q+16, q+32, q+48 hold partials) ----
  l_i = xadd16(l_i);
  l_i = xadd32(l_i);

  // ---- normalize (incl. OSCALE un-scaling of V) + write ctx (bf16) ----
  float inv = OSCALE / l_i;
  size_t qrow = (size_t)b * S_ + q0 + wv * 16 + (l & 15);
  #pragma unroll
  for (int m = 0; m < 4; ++m) {
    *(ushort4*)&ctx[qrow * D_ + c0 + m * 16 + (l >> 4) * 4] =
      make_ushort4(f2b(ot[m][0] * inv), f2b(ot[m][1] * inv),
                   f2b(ot[m][2] * inv), f2b(ot[m][3] * inv));
  }
}

// ---------------- bf16 MFMA GEMM: C[M,N] = A[M,K] * W[N,K]^T + bias ----------------
// BM=128 fixed; BN (128/64), BK (64/128) templated. BK=128 halves the
// per-k-iteration barrier drains — use only where occupancy is grid-capped.
template <int BN, int BK, int RELU, int OUTF32, int OUTB16>
__global__ __launch_bounds__(256) void gemm_bf16(const ushort* __restrict__ A,
                                                 const ushort* __restrict__ Bw,
                                                 const float* __restrict__ bias,
                                                 float* __restrict__ Cf,
                                                 ushort* __restrict__ Cb,
                                                 int M, int N, int K, int ntn) {
  const int NF   = BN / 32;          // n-frags per wave (4 or 2)
  const int ACW  = (128 * BK) / 2048; // A 1KB-chunks per wave
  const int BCW  = (BN  * BK) / 2048; // B 1KB-chunks per wave
  const int RPC  = 512 / BK;         // rows per 1KB chunk
  const int LPR  = BK / 8;           // 16B blocks per row
  __shared__ ushort As[128 * BK];
  __shared__ ushort Bs[BN * BK];
  int nwg = gridDim.x;
  int tile = blockIdx.x;
  int cpx = nwg >> 3;                         // grids are %8 == 0
  tile = (tile & 7) * cpx + (tile >> 3);      // XCD-contiguous remap
  int tm = tile / ntn, tn = tile % ntn;
  int m0 = tm * 128, n0 = tn * BN;
  int t = threadIdx.x, l = t & 63, wv = t >> 6;
  int wm = (wv >> 1) * 64, wn = (wv & 1) * (BN / 2);

  f32x4 zero = {0.f, 0.f, 0.f, 0.f};
  f32x4 acc[4][NF];
  #pragma unroll
  for (int m = 0; m < 4; ++m)
    #pragma unroll
    for (int n = 0; n < NF; ++n) acc[m][n] = zero;

  for (int k0 = 0; k0 < K; k0 += BK) {
    __syncthreads();
    #pragma unroll
    for (int c4 = 0; c4 < ACW; ++c4) {
      int jc = wv * ACW + c4;
      int r  = jc * RPC + l / LPR;
      int cs = (l % LPR) ^ (r & 7);
      gload_lds16(A + (size_t)(m0 + r) * K + k0 + cs * 8, &As[jc * 512]);
    }
    #pragma unroll
    for (int c4 = 0; c4 < BCW; ++c4) {
      int jc = wv * BCW + c4;
      int r  = jc * RPC + l / LPR;
      int cs = (l % LPR) ^ (r & 7);
      gload_lds16(Bw + (size_t)(n0 + r) * K + k0 + cs * 8, &Bs[jc * 512]);
    }
    __syncthreads();
    #pragma unroll
    for (int ks = 0; ks < BK / 32; ++ks) {
      bf16x8 af[4], bf[NF];
      #pragma unroll
      for (int m = 0; m < 4; ++m) {
        int r = wm + m * 16 + (l & 15);
        int c = (ks * 4 + (l >> 4)) ^ (r & 7);
        af[m] = *(const bf16x8*)&As[r * BK + c * 8];
      }
      #pragma unroll
      for (int n = 0; n < NF; ++n) {
        int r = wn + n * 16 + (l & 15);
        int c = (ks * 4 + (l >> 4)) ^ (r & 7);
        bf[n] = *(const bf16x8*)&Bs[r * BK + c * 8];
      }
      #pragma unroll
      for (int m = 0; m < 4; ++m)
        #pragma unroll
        for (int n = 0; n < NF; ++n)
          acc[m][n] = __builtin_amdgcn_mfma_f32_16x16x32_bf16(af[m], bf[n], acc[m][n], 0, 0, 0);
    }
  }

  float bv[NF];
  #pragma unroll
  for (int n = 0; n < NF; ++n) bv[n] = bias[n0 + wn + n * 16 + (l & 15)];
  #pragma unroll
  for (int m = 0; m < 4; ++m) {
    int row = m0 + wm + m * 16 + (l >> 4) * 4;
    #pragma unroll
    for (int n = 0; n < NF; ++n) {
      int col = n0 + wn + n * 16 + (l & 15);
      #pragma unroll
      for (int r = 0; r < 4; ++r) {
        float v = acc[m][n][r] + bv[n];
        if (RELU) v = fmaxf(v, 0.f);
        if (OUTF32) Cf[(size_t)(row + r) * N + col] = v;
        if (OUTB16) Cb[(size_t)(row + r) * N + col] = f2b(v);
      }
    }
  }
}

// -------- LayerNorm(bf16 in)*scale+bias + addscale*(bf16 add) -> f32 or bf16 --------
template <int OUTF32>
__global__ __launch_bounds__(256) void ln_b16_kernel(const ushort* __restrict__ in,
                                                     const float* __restrict__ scale,
                                                     const float* __restrict__ bias,
                                                     const ushort* __restrict__ add,
                                                     float addscale,
                                                     float* __restrict__ outf,
                                                     ushort* __restrict__ outb) {
  int row = blockIdx.x * 4 + (threadIdx.x >> 6);
  int lane = threadIdx.x & 63;
  u16x8 iv = *(const u16x8*)&in[(size_t)row * D_ + lane * 8];
  float v[8];
  float sum = 0.f, ss = 0.f;
  #pragma unroll
  for (int i = 0; i < 8; ++i) {
    v[i] = b2f(iv[i]);
    sum += v[i];
    ss += v[i] * v[i];
  }
  #pragma unroll
  for (int off = 1; off < 16; off <<= 1) {
    sum += __shfl_xor(sum, off);
    ss  += __shfl_xor(ss, off);
  }
  sum = xadd16(sum); sum = xadd32(sum);
  ss  = xadd16(ss);  ss  = xadd32(ss);
  float mean = sum * (1.f / D_);
  float var = ss * (1.f / D_) - mean * mean;
  float rstd = rsqrtf(var + EPSF);

  u16x8 av = *(const u16x8*)&add[(size_t)row * D_ + lane * 8];
  float4 s0 = *(const float4*)&scale[lane * 8];
  float4 s1 = *(const float4*)&scale[lane * 8 + 4];
  float4 b0 = *(const float4*)&bias[lane * 8];
  float4 b1 = *(const float4*)&bias[lane * 8 + 4];
  float sc[8] = {s0.x, s0.y, s0.z, s0.w, s1.x, s1.y, s1.z, s1.w};
  float bi[8] = {b0.x, b0.y, b0.z, b0.w, b1.x, b1.y, b1.z, b1.w};
  float o[8];
  #pragma unroll
  for (int i = 0; i < 8; ++i)
    o[i] = (v[i] - mean) * rstd * sc[i] + bi[i] + b2f(av[i]) * addscale;

  if (OUTF32) {
    float* op = outf + (size_t)row * D_ + lane * 8;
    *(float4*)op       = make_float4(o[0], o[1], o[2], o[3]);
    *(float4*)(op + 4) = make_float4(o[4], o[5], o[6], o[7]);
  } else {
    u16x8 ob;
    #pragma unroll
    for (int i = 0; i < 8; ++i) ob[i] = f2b(o[i]);
    *(u16x8*)&outb[(size_t)row * D_ + lane * 8] = ob;
  }
}

extern "C" void kernel_launch(void* const* d_in, const int* in_sizes, int n_in,
                              void* d_out, int out_size, void* d_ws, size_t ws_size,
                              hipStream_t stream) {
  const float* x      = (const float*)d_in[0];
  const float* Wo_w   = (const float*)d_in[3];
  const float* Wo_b   = (const float*)d_in[4];
  const float* ln_a_s = (const float*)d_in[5];
  const float* ln_a_b = (const float*)d_in[6];
  const float* W1_w   = (const float*)d_in[7];
  const float* W1_b   = (const float*)d_in[8];
  const float* W2_w   = (const float*)d_in[9];
  const float* W2_b   = (const float*)d_in[10];
  const float* ln_f_s = (const float*)d_in[11];
  const float* ln_f_b = (const float*)d_in[12];
  float* out = (float*)d_out;

  char* ws = (char*)d_ws;
  const size_t MB = 1024 * 1024;
  ushort* xbb  = (ushort*)(ws);                 // 8 MB   [B,S,D] bf16 (scaled)
  ushort* xTb  = (ushort*)(ws + 8 * MB);        // 8 MB   [B,D,S] bf16 (scaled)
  ushort* wob  = (ushort*)(ws + 16 * MB);       // 0.5 MB
  ushort* w1b  = (ushort*)(ws + 17 * MB);       // 2 MB
  ushort* w2b  = (ushort*)(ws + 19 * MB);       // 2 MB
  ushort* ctxb = (ushort*)(ws + 21 * MB);       // 8 MB
  ushort* x1b  = (ushort*)(ws + 29 * MB);       // 8 MB
  ushort* tmpb = (ushort*)(ws + 37 * MB);       // 8 MB  [NTOK,D] bf16 pre-LN
  ushort* hb   = (ushort*)(ws + 45 * MB);       // 32 MB (ends at 77 MB)

  // x -> bf16 (straight + transposed, pre-scaled)
  prep_kernel<<<B_ * (S_ / 64) * (D_ / 64), 256, 0, stream>>>(x, xbb, xTb);

  // attention (WGs 0..511) + weight cvt tail (WGs 512..1087, overlapped)
  attn_mfma<<<512 + 576, 512, 0, stream>>>(xbb, xTb, ctxb,
                                           Wo_w, wob, (D_ * D_) / 8,
                                           W1_w, w1b, (DFF_ * D_) / 8,
                                           W2_w, w2b, (D_ * DFF_) / 8);

  // attn_out(pre-LN) = ctx @ Wo^T + b -> tmpb (bf16)   [BN=64, BK=128: 512 WGs]
  gemm_bf16<64, 128, 0, 0, 1><<<(NTOK / 128) * (D_ / 64), 256, 0, stream>>>(
      ctxb, wob, Wo_b, nullptr, tmpb, NTOK, D_, D_, D_ / 64);

  // x1 = LN(tmpb) + xbb*OSCALE -> x1b (bf16)
  ln_b16_kernel<0><<<NTOK / 4, 256, 0, stream>>>(tmpb, ln_a_s, ln_a_b, xbb, OSCALE,
                                                 nullptr, x1b);

  // h = relu(x1 @ W1^T + b1) -> hb (bf16)   [BN=128, BK=64: 1024 WGs, 4 WG/CU]
  gemm_bf16<128, 64, 1, 0, 1><<<(NTOK / 128) * (DFF_ / 128), 256, 0, stream>>>(
      x1b, w1b, W1_b, nullptr, hb, NTOK, DFF_, D_, DFF_ / 128);

  // ffn(pre-LN) = h @ W2^T + b2 -> tmpb (bf16)   [BN=64, BK=128: 512 WGs]
  gemm_bf16<64, 128, 0, 0, 1><<<(NTOK / 128) * (D_ / 64), 256, 0, stream>>>(
      hb, w2b, W2_b, nullptr, tmpb, NTOK, D_, DFF_, D_ / 64);

  // out = LN(tmpb) + x1b (f32 final)
  ln_b16_kernel<1><<<NTOK / 4, 256, 0, stream>>>(tmpb, ln_f_s, ln_f_b, x1b, 1.0f,
                                                 out, nullptr);
}